// Round 1
// baseline (112.256 us; speedup 1.0000x reference)
//
#include <hip/hip_runtime.h>

#define DK 256   // feature dim (K)
#define TT 1024  // T1 = T2
#define NB 16    // batch

typedef __attribute__((ext_vector_type(8))) short bf16x8;
typedef __attribute__((ext_vector_type(4))) float f32x4;

// round-to-nearest-even fp32 -> bf16 (inputs are finite normals)
__device__ __forceinline__ unsigned short f2bf(float f) {
    unsigned int u = __float_as_uint(f);
    unsigned int r = 0x7fffu + ((u >> 16) & 1u);
    return (unsigned short)((u + r) >> 16);
}

// ---------------------------------------------------------------------------
// Prep: xw = bf16(x * w3), yb = bf16(y), tx = x . w1, ty = y . w2
// One wave per row of 256 elements: lane handles float4 at d = lane*4.
// ---------------------------------------------------------------------------
__global__ __launch_bounds__(256) void prep_kernel(
    const float* __restrict__ x, const float* __restrict__ y,
    const float* __restrict__ WS,
    unsigned short* __restrict__ xw, unsigned short* __restrict__ yb,
    float* __restrict__ tx, float* __restrict__ ty)
{
    const int wid  = threadIdx.x >> 6;
    const int lane = threadIdx.x & 63;
    const int row  = blockIdx.x * 4 + wid;       // 0 .. 2*NB*TT-1 (wave-uniform)
    const bool is_x = row < NB * TT;
    const int r = is_x ? row : row - NB * TT;

    const float4 wmul = is_x ? ((const float4*)(WS + 2 * DK))[lane]
                             : make_float4(1.f, 1.f, 1.f, 1.f);
    const float4 wdot = is_x ? ((const float4*)WS)[lane]
                             : ((const float4*)(WS + DK))[lane];

    const float4 v = ((const float4*)((is_x ? x : y) + (size_t)r * DK))[lane];

    float partial = v.x * wdot.x + v.y * wdot.y + v.z * wdot.z + v.w * wdot.w;

    ushort4 o;
    o.x = f2bf(v.x * wmul.x);
    o.y = f2bf(v.y * wmul.y);
    o.z = f2bf(v.z * wmul.z);
    o.w = f2bf(v.w * wmul.w);
    ((ushort4*)((is_x ? xw : yb) + (size_t)r * DK))[lane] = o;

    #pragma unroll
    for (int off = 32; off > 0; off >>= 1)
        partial += __shfl_down(partial, off);
    if (lane == 0) (is_x ? tx : ty)[r] = partial;
}

// ---------------------------------------------------------------------------
// GEMM: out[b, i, j] = sum_k xw[b,i,k] * yb[b,j,k] + tx[b,i] + ty[b,j]
// 128x128 tile, BK=64, 4 waves in 2x2 (64x64 each), 16x16x32 bf16 MFMA.
// LDS layout: per tile-row m (64 bf16 = 8 chunks of 16B), chunk kc stored at
// slot (kc ^ (m & 7)). global_load_lds dest = wave-uniform base + lane*16
// stays contiguous; ds_read_b128 fragment reads become conflict-free
// (2-way max, which is free).
// ---------------------------------------------------------------------------
__device__ __forceinline__ void gl_lds16(const unsigned short* g,
                                         unsigned short* l)
{
    __builtin_amdgcn_global_load_lds(
        (const __attribute__((address_space(1))) void*)g,
        (__attribute__((address_space(3))) void*)l,
        16, 0, 0);
}

__global__ __launch_bounds__(256) void gemm_kernel(
    const unsigned short* __restrict__ xw, const unsigned short* __restrict__ yb,
    const float* __restrict__ tx, const float* __restrict__ ty,
    float* __restrict__ out)
{
    __shared__ unsigned short As[128 * 64];
    __shared__ unsigned short Bs[128 * 64];
    __shared__ float txs[128];
    __shared__ float tys[128];

    const int tid  = threadIdx.x;
    const int w    = tid >> 6;
    const int lane = tid & 63;
    const int wi   = w >> 1;      // wave row (0..1)
    const int wj   = w & 1;       // wave col (0..1)
    const int batch = blockIdx.z;
    const int it = blockIdx.y;    // i tile (0..7)
    const int jt = blockIdx.x;    // j tile (0..7)

    const unsigned short* gA = xw + ((size_t)batch * TT + it * 128) * DK;
    const unsigned short* gB = yb + ((size_t)batch * TT + jt * 128) * DK;

    if (tid < 128) txs[tid] = tx[batch * TT + it * 128 + tid];
    else           tys[tid - 128] = ty[batch * TT + jt * 128 + tid - 128];

    f32x4 acc[4][4];
    #pragma unroll
    for (int i = 0; i < 4; ++i)
        #pragma unroll
        for (int j = 0; j < 4; ++j)
            acc[i][j] = (f32x4){0.f, 0.f, 0.f, 0.f};

    const int mfr  = lane & 15;   // row/col within 16x16 fragment
    const int quad = lane >> 4;

    #pragma unroll
    for (int kt = 0; kt < 4; ++kt) {
        // ---- stage A+B tile (128 rows x 64 bf16 each) via global_load_lds
        #pragma unroll
        for (int q = 0; q < 4; ++q) {
            const int m0   = w * 32 + q * 8;        // wave-uniform row base
            const int m    = m0 + (lane >> 3);      // 8 rows per instruction
            const int slot = lane & 7;              // LDS chunk slot
            const int kc   = slot ^ (m & 7);        // global 16B chunk idx
            gl_lds16(gA + (size_t)m * DK + kt * 64 + kc * 8, As + m0 * 64);
            gl_lds16(gB + (size_t)m * DK + kt * 64 + kc * 8, Bs + m0 * 64);
        }
        __syncthreads();

        // ---- compute: 2 MFMA K-steps of 32
        #pragma unroll
        for (int ks = 0; ks < 2; ++ks) {
            const int kc = ks * 4 + quad;           // 16B chunk this quad reads
            bf16x8 av[4], bv[4];
            #pragma unroll
            for (int mi = 0; mi < 4; ++mi) {
                const int m = wi * 64 + mi * 16 + mfr;
                av[mi] = *(const bf16x8*)(As + m * 64 + (kc ^ (m & 7)) * 8);
                const int n = wj * 64 + mi * 16 + mfr;
                bv[mi] = *(const bf16x8*)(Bs + n * 64 + (kc ^ (n & 7)) * 8);
            }
            #pragma unroll
            for (int mi = 0; mi < 4; ++mi)
                #pragma unroll
                for (int ni = 0; ni < 4; ++ni)
                    acc[mi][ni] = __builtin_amdgcn_mfma_f32_16x16x32_bf16(
                        av[mi], bv[ni], acc[mi][ni], 0, 0, 0);
        }
        __syncthreads();
    }

    // ---- epilogue: + tx[i] + ty[j], fp32 store
    float* outB = out + ((size_t)batch << 20) + (size_t)(it * 128) * TT + jt * 128;
    #pragma unroll
    for (int mi = 0; mi < 4; ++mi) {
        #pragma unroll
        for (int r = 0; r < 4; ++r) {
            const int row = wi * 64 + mi * 16 + quad * 4 + r;
            const float trow = txs[row];
            #pragma unroll
            for (int ni = 0; ni < 4; ++ni) {
                const int col = wj * 64 + ni * 16 + mfr;
                outB[(size_t)row * TT + col] = acc[mi][ni][r] + trow + tys[col];
            }
        }
    }
}

// ---------------------------------------------------------------------------
// Fallback (only if workspace too small): naive fp32, correctness net.
// ---------------------------------------------------------------------------
__global__ __launch_bounds__(256) void naive_kernel(
    const float* __restrict__ x, const float* __restrict__ y,
    const float* __restrict__ WS, float* __restrict__ out)
{
    size_t idx = (size_t)blockIdx.x * 256 + threadIdx.x;
    if (idx >= (size_t)NB * TT * TT) return;
    const int b = (int)(idx >> 20);
    const int i = (int)((idx >> 10) & (TT - 1));
    const int j = (int)(idx & (TT - 1));
    const float* xp = x + ((size_t)b * TT + i) * DK;
    const float* yp = y + ((size_t)b * TT + j) * DK;
    float s = 0.f, sx = 0.f, sy = 0.f;
    for (int d = 0; d < DK; ++d) {
        const float xv = xp[d], yv = yp[d];
        s  += xv * WS[2 * DK + d] * yv;
        sx += xv * WS[d];
        sy += yv * WS[DK + d];
    }
    out[idx] = s + sx + sy;
}

extern "C" void kernel_launch(void* const* d_in, const int* in_sizes, int n_in,
                              void* d_out, int out_size, void* d_ws, size_t ws_size,
                              hipStream_t stream)
{
    const float* x  = (const float*)d_in[0];
    const float* y  = (const float*)d_in[1];
    const float* WS = (const float*)d_in[2];
    float* out = (float*)d_out;

    const size_t n_xy = (size_t)NB * TT * DK;           // 4,194,304 elements
    const size_t need = n_xy * 2 * sizeof(unsigned short)   // xw + yb
                      + (size_t)NB * TT * 2 * sizeof(float); // tx + ty

    if (ws_size >= need) {
        unsigned short* xw = (unsigned short*)d_ws;
        unsigned short* yb = xw + n_xy;
        float* tx = (float*)(yb + n_xy);
        float* ty = tx + NB * TT;

        prep_kernel<<<dim3((2 * NB * TT) / 4), dim3(256), 0, stream>>>(
            x, y, WS, xw, yb, tx, ty);
        gemm_kernel<<<dim3(8, 8, NB), dim3(256), 0, stream>>>(
            xw, yb, tx, ty, out);
    } else {
        naive_kernel<<<dim3((NB * TT * TT + 255) / 256), dim3(256), 0, stream>>>(
            x, y, WS, out);
    }
}